// Round 7
// baseline (13179.012 us; speedup 1.0000x reference)
//
#include <hip/hip_runtime.h>
#include <stdint.h>

// Problem sizes (fixed)
#define BATCH 256
#define HDIM  256
#define MDIM  128
#define NSTEPS 512

typedef unsigned short u16;
typedef unsigned int   u32;
typedef short short8 __attribute__((ext_vector_type(8)));
typedef float f32x4  __attribute__((ext_vector_type(4)));

__device__ __forceinline__ u16 f2bf(float f) {
    u32 x = __builtin_bit_cast(u32, f);
    u32 r = x + 0x7FFFu + ((x >> 16) & 1u);
    return (u16)(r >> 16);
}
__device__ __forceinline__ float bf2f(u16 h) {
    u32 x = ((u32)h) << 16;
    return __builtin_bit_cast(float, x);
}
__device__ __forceinline__ float sigm(float x) { return 1.f / (1.f + __expf(-x)); }
__device__ __forceinline__ float tanh_f(float x) {
    float ax = fabsf(x);
    float e  = __expf(-2.f * ax);
    float t  = (1.f - e) / (1.f + e);
    return copysignf(t, x);
}
__device__ __forceinline__ f32x4 mfma16(short8 a, short8 b, f32x4 c) {
    return __builtin_amdgcn_mfma_f32_16x16x32_bf16(a, b, c, 0, 0, 0);
}

// ---------------------------------------------------------------------------
// prep: effective weights, bf16 hi/lo split, bias vector.
// Weff rows: [0,256)=r (w_ih+w_hh), [256,512)=z (sum), [512,768)=i_n (w_ih),
//            [768,1024)=h_n (w_hh), [1024,1152)=out_w.  bias same rows.
// ---------------------------------------------------------------------------
__global__ __launch_bounds__(256) void k_prep(
    const float* __restrict__ w_ih, const float* __restrict__ w_hh,
    const float* __restrict__ b_ih, const float* __restrict__ b_hh,
    const float* __restrict__ ow,   const float* __restrict__ obv,
    u16* __restrict__ Whi, u16* __restrict__ Wlo, float* __restrict__ bias) {
    int row = blockIdx.x;   // 0..1151
    int c   = threadIdx.x;  // 0..255
    float v;
    if (row < 512)        v = w_ih[row * HDIM + c] + w_hh[row * HDIM + c];
    else if (row < 768)   v = w_ih[row * HDIM + c];
    else if (row < 1024)  v = w_hh[(row - 256) * HDIM + c];
    else                  v = ow[(row - 1024) * HDIM + c];
    u16 hi = f2bf(v);
    u16 lo = f2bf(v - bf2f(hi));
    Whi[(size_t)row * HDIM + c] = hi;
    Wlo[(size_t)row * HDIM + c] = lo;
    if (c == 0) {
        float bv;
        if (row < 512)        bv = b_ih[row] + b_hh[row];
        else if (row < 768)   bv = b_ih[row];
        else if (row < 1024)  bv = b_hh[row - 256];
        else                  bv = obv[row - 1024];
        bias[row] = bv;
    }
}

// ---------------------------------------------------------------------------
// f32 tiled GEMM (prologue FNN): out[M][N] = act(A @ W^T + b)
// ---------------------------------------------------------------------------
template <int RELU>
__global__ __launch_bounds__(256) void k_gemm_f32(
    const float* __restrict__ A, const float* __restrict__ W,
    const float* __restrict__ bvec, float* __restrict__ out, int N, int K) {
    __shared__ float At[16][17];
    __shared__ float Wt[16][17];
    int tx = threadIdx.x, ty = threadIdx.y;
    int mrow = blockIdx.x * 16 + ty;
    int nrow = blockIdx.y * 16 + ty;
    float acc = 0.0f;
    for (int k0 = 0; k0 < K; k0 += 16) {
        At[ty][tx] = A[(size_t)mrow * K + k0 + tx];
        Wt[ty][tx] = W[(size_t)nrow * K + k0 + tx];
        __syncthreads();
#pragma unroll
        for (int kk = 0; kk < 16; ++kk) acc += At[ty][kk] * Wt[tx][kk];
        __syncthreads();
    }
    int n = blockIdx.y * 16 + tx;
    float r = acc + bvec[n];
    if (RELU) r = fmaxf(r, 0.0f);
    out[(size_t)mrow * N + n] = r;
}

// ---------------------------------------------------------------------------
// Persistent scan: 16 blocks (one per 16-row batch cluster) x 1024 threads
// (16 waves). Wave w owns h-cols [16w,16w+16) of all 4 gates (B-frags in
// VGPRs, hi+lo) + proj cols [16w,16w+16) for w<8 (hi only). h exchanged via
// double-buffered XOR-swizzled LDS (bf16); hold[] keeps exact f32 h. One raw
// s_barrier + lgkmcnt(0) per step (global stores never drained in-loop).
// ---------------------------------------------------------------------------
__global__ __launch_bounds__(1024) void k_scan(
    const u16* __restrict__ Whi, const u16* __restrict__ Wlo,
    const float* __restrict__ bias,
    const float* __restrict__ hx, const float* __restrict__ w_hh,
    const float* __restrict__ b_ih, const float* __restrict__ b_hh,
    float* __restrict__ out1, float* __restrict__ out2) {

    __shared__ uint4 hbuf4[2][512];   // 2 x 8KB: h as bf16 [16][256], swizzled

    const int g     = blockIdx.x;
    const int tid   = threadIdx.x;
    const int wid   = tid >> 6;
    const int lane  = tid & 63;
    const int col_l = lane & 15;
    const int kgrp  = lane >> 4;
    const int kofs  = kgrp * 8;
    const int r0    = kgrp * 4;          // C rows r0..r0+3 (m89 layout)
    const int jcol  = wid * 16 + col_l;  // owned h-column

    // ---- B fragments: gates hi+lo, proj hi (one-time global loads) ----
    short8 bhi[4][8], blo[4][8];
#pragma unroll
    for (int g4 = 0; g4 < 4; ++g4) {
        int R = g4 * 256 + jcol;
#pragma unroll
        for (int kt = 0; kt < 8; ++kt) {
            size_t idx = (size_t)R * HDIM + kt * 32 + kofs;
            bhi[g4][kt] = *(const short8*)(Whi + idx);
            blo[g4][kt] = *(const short8*)(Wlo + idx);
        }
    }
    short8 phi[8];
    if (wid < 8) {
        int R = 1024 + wid * 16 + col_l;
#pragma unroll
        for (int kt = 0; kt < 8; ++kt)
            phi[kt] = *(const short8*)(Whi + (size_t)R * HDIM + kt * 32 + kofs);
    }

    const float b_r  = bias[jcol];
    const float b_z  = bias[256 + jcol];
    const float b_in = bias[512 + jcol];
    const float b_hn = bias[768 + jcol];
    const float ob   = (wid < 8) ? bias[1024 + wid * 16 + col_l] : 0.f;

    // ---- step 0 (one-time VALU): h_1 = cell(x=0, h=hx); needs raw w_hh ----
    float hold[4];
    {
        float ghr[4] = {0, 0, 0, 0}, ghz[4] = {0, 0, 0, 0}, ghn[4] = {0, 0, 0, 0};
        const float* wr  = w_hh + (size_t)jcol * HDIM;
        const float* wz  = w_hh + (size_t)(256 + jcol) * HDIM;
        const float* wn  = w_hh + (size_t)(512 + jcol) * HDIM;
        const float* hx0 = hx + (size_t)(g * 16 + r0) * HDIM;
        for (int k = 0; k < HDIM; ++k) {
            float fr = wr[k], fz = wz[k], fn = wn[k];
#pragma unroll
            for (int i = 0; i < 4; ++i) {
                float h = hx0[i * HDIM + k];
                ghr[i] += h * fr; ghz[i] += h * fz; ghn[i] += h * fn;
            }
        }
        char* hb1 = (char*)hbuf4[1];
#pragma unroll
        for (int i = 0; i < 4; ++i) {
            float rr = sigm(b_ih[jcol] + b_hh[jcol] + ghr[i]);
            float zz = sigm(b_ih[256 + jcol] + b_hh[256 + jcol] + ghz[i]);
            float nn = tanh_f(b_ih[512 + jcol] + rr * (ghn[i] + b_hh[512 + jcol]));
            float hv = nn + zz * (hx0[i * HDIM + jcol] - nn);
            hold[i] = hv;
            int row  = r0 + i;
            int byte = (row * 512 + jcol * 2) ^ ((row & 7) << 4);
            *(u16*)(hb1 + byte) = f2bf(hv);
        }
    }
    asm volatile("s_waitcnt lgkmcnt(0)" ::: "memory");
    __builtin_amdgcn_s_barrier();
    __builtin_amdgcn_sched_barrier(0);

    // ---- main loop: step s reads h_s (buf s&1), writes h_{s+1}, projects t=s-1 ----
    for (int s = 1; s <= 511; ++s) {
        const char* hb = (const char*)hbuf4[s & 1];
        short8 a[8];
#pragma unroll
        for (int kt = 0; kt < 8; ++kt) {
            int byte = (col_l * 512 + kt * 64 + kgrp * 16) ^ ((col_l & 7) << 4);
            a[kt] = *(const short8*)(hb + byte);
        }
        f32x4 acc[4];
#pragma unroll
        for (int n = 0; n < 4; ++n) acc[n] = (f32x4){0.f, 0.f, 0.f, 0.f};
        f32x4 oacc = (f32x4){0.f, 0.f, 0.f, 0.f};
#pragma unroll
        for (int kt = 0; kt < 8; ++kt) {
#pragma unroll
            for (int g4 = 0; g4 < 4; ++g4) {
                acc[g4] = mfma16(a[kt], bhi[g4][kt], acc[g4]);
                acc[g4] = mfma16(a[kt], blo[g4][kt], acc[g4]);
            }
        }
        if (wid < 8) {
#pragma unroll
            for (int kt = 0; kt < 8; ++kt) oacc = mfma16(a[kt], phi[kt], oacc);
        }

        char* ho = (char*)hbuf4[(s + 1) & 1];
#pragma unroll
        for (int i = 0; i < 4; ++i) {
            float rr = sigm(acc[0][i] + b_r);
            float zz = sigm(acc[1][i] + b_z);
            float nn = tanh_f(acc[2][i] + b_in + rr * (acc[3][i] + b_hn));
            float hv = nn + zz * (hold[i] - nn);
            hold[i] = hv;
            int row  = r0 + i;
            int byte = (row * 512 + jcol * 2) ^ ((row & 7) << 4);
            *(u16*)(ho + byte) = f2bf(hv);
        }
        if (wid < 8) {
#pragma unroll
            for (int i = 0; i < 4; ++i)
                out1[(size_t)(g * 16 + r0 + i) * (NSTEPS * MDIM) +
                     (size_t)(s - 1) * MDIM + wid * 16 + col_l] = oacc[i] + ob;
        }
        asm volatile("s_waitcnt lgkmcnt(0)" ::: "memory");
        __builtin_amdgcn_s_barrier();
        __builtin_amdgcn_sched_barrier(0);
    }

    // ---- epilogue: t=511 = proj(h_512) from buf 0; out2 = exact f32 h_512 ----
    if (wid < 8) {
        const char* hb = (const char*)hbuf4[0];
        short8 a[8];
#pragma unroll
        for (int kt = 0; kt < 8; ++kt) {
            int byte = (col_l * 512 + kt * 64 + kgrp * 16) ^ ((col_l & 7) << 4);
            a[kt] = *(const short8*)(hb + byte);
        }
        f32x4 oacc = (f32x4){0.f, 0.f, 0.f, 0.f};
#pragma unroll
        for (int kt = 0; kt < 8; ++kt) oacc = mfma16(a[kt], phi[kt], oacc);
#pragma unroll
        for (int i = 0; i < 4; ++i)
            out1[(size_t)(g * 16 + r0 + i) * (NSTEPS * MDIM) +
                 511ull * MDIM + wid * 16 + col_l] = oacc[i] + ob;
    }
#pragma unroll
    for (int i = 0; i < 4; ++i)
        out2[(size_t)(g * 16 + r0 + i) * HDIM + jcol] = hold[i];
}

// ---------------------------------------------------------------------------
extern "C" void kernel_launch(void* const* d_in, const int* in_sizes, int n_in,
                              void* d_out, int out_size, void* d_ws, size_t ws_size,
                              hipStream_t stream) {
    const float* P[11];
    for (int i = 0; i < 11 && i < n_in; ++i) P[i] = (const float*)d_in[i];

    // Input-order detection via element-count signature (dict order confirmed
    // by round-6 pass; keep insurance).
    const float *emb, *w1, *b1, *w2, *b2, *w_ih, *b_ih, *w_hh, *b_hh, *ow, *obv;
    if (n_in > 1 && in_sizes[1] == 256) {            // alphabetical
        emb = P[0]; b1 = P[1]; b2 = P[2]; w1 = P[3]; w2 = P[4];
        b_hh = P[5]; b_ih = P[6]; w_hh = P[7]; w_ih = P[8];
        obv = P[9]; ow = P[10];
    } else if (n_in > 1 && in_sizes[1] == 32768) {   // reversed dict
        obv = P[0]; ow = P[1]; b_hh = P[2]; w_hh = P[3]; b_ih = P[4];
        w_ih = P[5]; b2 = P[6]; w2 = P[7]; b1 = P[8]; w1 = P[9]; emb = P[10];
    } else {                                         // dict order (documented)
        emb = P[0]; w1 = P[1]; b1 = P[2]; w2 = P[3]; b2 = P[4];
        w_ih = P[5]; b_ih = P[6]; w_hh = P[7]; b_hh = P[8];
        ow = P[9]; obv = P[10];
    }

    float* out1 = (float*)d_out;                            // [256][512][128] f32
    float* out2 = out1 + (size_t)BATCH * NSTEPS * MDIM;     // [256][256] f32

    // ws layout (~1.63 MB)
    char* ws = (char*)d_ws;
    u16*   Whi  = (u16*)(ws + 0);            // 1152*256*2 = 589824
    u16*   Wlo  = (u16*)(ws + 589824);       // 589824
    float* bias = (float*)(ws + 1179648);    // 4608
    float* mid  = (float*)(ws + 1184256);    // 262144
    float* hxb  = (float*)(ws + 1446400);    // 262144  (ends 1708544)

    k_prep<<<1152, 256, 0, stream>>>(w_ih, w_hh, b_ih, b_hh, ow, obv, Whi, Wlo, bias);
    // FNN: hx = relu(emb@w1^T + b1) @ w2^T + b2
    k_gemm_f32<1><<<dim3(16, 16), dim3(16, 16), 0, stream>>>(emb, w1, b1, mid, 256, 256);
    k_gemm_f32<0><<<dim3(16, 16), dim3(16, 16), 0, stream>>>(mid, w2, b2, hxb, 256, 256);
    // Persistent scan (steps 0..511 + fused projection + finals)
    k_scan<<<16, 1024, 0, stream>>>(Whi, Wlo, bias, hxb, w_hh, b_ih, b_hh, out1, out2);
}

// Round 8
// 4295.004 us; speedup vs baseline: 3.0685x; 3.0685x over previous
//
#include <hip/hip_runtime.h>
#include <stdint.h>

// Problem sizes (fixed)
#define BATCH 256
#define HDIM  256
#define MDIM  128
#define NSTEPS 512

typedef unsigned short u16;
typedef unsigned int   u32;
typedef short short8 __attribute__((ext_vector_type(8)));
typedef float f32x4  __attribute__((ext_vector_type(4)));

__device__ __forceinline__ u16 f2bf(float f) {
    u32 x = __builtin_bit_cast(u32, f);
    u32 r = x + 0x7FFFu + ((x >> 16) & 1u);
    return (u16)(r >> 16);
}
__device__ __forceinline__ float bf2f(u16 h) {
    u32 x = ((u32)h) << 16;
    return __builtin_bit_cast(float, x);
}
__device__ __forceinline__ float sigm(float x) { return 1.f / (1.f + __expf(-x)); }
__device__ __forceinline__ float tanh_f(float x) {
    float ax = fabsf(x);
    float e  = __expf(-2.f * ax);
    float t  = (1.f - e) / (1.f + e);
    return copysignf(t, x);
}
__device__ __forceinline__ f32x4 mfma16(short8 a, short8 b, f32x4 c) {
    return __builtin_amdgcn_mfma_f32_16x16x32_bf16(a, b, c, 0, 0, 0);
}

// ---------------------------------------------------------------------------
// prep: effective weights (x==h for steps>=1 collapses r,z to summed weights),
// bf16 hi/lo split, bias vector, flag zeroing.
// Weff rows: [0,256)=r (w_ih+w_hh), [256,512)=z (sum), [512,768)=i_n (w_ih),
//            [768,1024)=h_n (w_hh), [1024,1152)=out_w.  bias same rows.
// ---------------------------------------------------------------------------
__global__ __launch_bounds__(256) void k_prep(
    const float* __restrict__ w_ih, const float* __restrict__ w_hh,
    const float* __restrict__ b_ih, const float* __restrict__ b_hh,
    const float* __restrict__ ow,   const float* __restrict__ obv,
    u16* __restrict__ Whi, u16* __restrict__ Wlo, float* __restrict__ bias,
    u32* __restrict__ flags) {
    int row = blockIdx.x;   // 0..1151
    int c   = threadIdx.x;  // 0..255
    float v;
    if (row < 512)        v = w_ih[row * HDIM + c] + w_hh[row * HDIM + c];
    else if (row < 768)   v = w_ih[row * HDIM + c];
    else if (row < 1024)  v = w_hh[(row - 256) * HDIM + c];
    else                  v = ow[(row - 1024) * HDIM + c];
    u16 hi = f2bf(v);
    u16 lo = f2bf(v - bf2f(hi));
    Whi[(size_t)row * HDIM + c] = hi;
    Wlo[(size_t)row * HDIM + c] = lo;
    if (c == 0) {
        float bv;
        if (row < 512)        bv = b_ih[row] + b_hh[row];
        else if (row < 768)   bv = b_ih[row];
        else if (row < 1024)  bv = b_hh[row - 256];
        else                  bv = obv[row - 1024];
        bias[row] = bv;
    }
    if (row == 0) flags[c] = 0u;   // 16 clusters x 16 blocks
}

// ---------------------------------------------------------------------------
// f32 tiled GEMM (prologue FNN): out[M][N] = act(A @ W^T + b)
// ---------------------------------------------------------------------------
template <int RELU>
__global__ __launch_bounds__(256) void k_gemm_f32(
    const float* __restrict__ A, const float* __restrict__ W,
    const float* __restrict__ bvec, float* __restrict__ out, int N, int K) {
    __shared__ float At[16][17];
    __shared__ float Wt[16][17];
    int tx = threadIdx.x, ty = threadIdx.y;
    int mrow = blockIdx.x * 16 + ty;
    int nrow = blockIdx.y * 16 + ty;
    float acc = 0.0f;
    for (int k0 = 0; k0 < K; k0 += 16) {
        At[ty][tx] = A[(size_t)mrow * K + k0 + tx];
        Wt[ty][tx] = W[(size_t)nrow * K + k0 + tx];
        __syncthreads();
#pragma unroll
        for (int kk = 0; kk < 16; ++kk) acc += At[ty][kk] * Wt[tx][kk];
        __syncthreads();
    }
    int n = blockIdx.y * 16 + tx;
    float r = acc + bvec[n];
    if (RELU) r = fmaxf(r, 0.0f);
    out[(size_t)mrow * N + n] = r;
}

// ---------------------------------------------------------------------------
// Persistent scan: 256 blocks x 64 threads (1 wave each, ~380 VGPR).
// Block (g,w): cluster g (16 batch rows), h-cols [16w,16w+16), all 4 gates
// resident in VGPRs (hi+lo). h_s exchanged via global bf16 double buffer
// (L2-resident; cluster pinned to one XCD by b&7 heuristic). Per step:
// spin(flags>=s) -> acquire -> load h_s -> 64 MFMA -> pointwise ->
// store h_{s+1} -> release -> flag=s+1 -> fused proj of t=s-1 (even t:
// blocks w<8, odd t: w>=8; proj stores issued after flag, off critical path).
// ---------------------------------------------------------------------------
__global__ __launch_bounds__(64, 1) void k_scan(
    const u16* __restrict__ Whi, const u16* __restrict__ Wlo,
    const float* __restrict__ bias,
    const float* __restrict__ hx, const float* __restrict__ w_hh,
    const float* __restrict__ b_ih, const float* __restrict__ b_hh,
    u16* __restrict__ exch, u32* __restrict__ flags,
    float* __restrict__ out1, float* __restrict__ out2) {

    const int b    = blockIdx.x;
    const int w    = b >> 4;                              // 0..15 col-group
    const int g    = ((b & 7) << 1) | ((b >> 3) & 1);     // cluster, XCD-pinned
    const int lane = threadIdx.x;
    const int col_l = lane & 15;
    const int kgrp  = lane >> 4;
    const int kofs  = kgrp * 8;
    const int r0    = kgrp * 4;          // C rows r0..r0+3 (m89 layout)
    const int jcol  = w * 16 + col_l;    // owned h-column
    const int pcol  = (w & 7) * 16 + col_l;  // owned proj column
    const int myt   = w >> 3;            // project t with (t&1)==myt

    // ---- resident B fragments: gates hi+lo (256 VGPR) + proj hi (32) ----
    short8 bhi[4][8], blo[4][8], phi[8];
#pragma unroll
    for (int g4 = 0; g4 < 4; ++g4) {
        const u16* base_hi = Whi + (size_t)(g4 * 256 + jcol) * HDIM;
        const u16* base_lo = Wlo + (size_t)(g4 * 256 + jcol) * HDIM;
#pragma unroll
        for (int kt = 0; kt < 8; ++kt) {
            bhi[g4][kt] = *(const short8*)(base_hi + kt * 32 + kofs);
            blo[g4][kt] = *(const short8*)(base_lo + kt * 32 + kofs);
        }
    }
    {
        const u16* base_p = Whi + (size_t)(1024 + pcol) * HDIM;
#pragma unroll
        for (int kt = 0; kt < 8; ++kt)
            phi[kt] = *(const short8*)(base_p + kt * 32 + kofs);
    }

    const float b_r  = bias[jcol];
    const float b_z  = bias[256 + jcol];
    const float b_in = bias[512 + jcol];
    const float b_hn = bias[768 + jcol];
    const float ob   = bias[1024 + pcol];

    u16* const eA = exch + (size_t)((g * 2 + 0) * 16) * HDIM;  // parity 0
    u16* const eB = exch + (size_t)((g * 2 + 1) * 16) * HDIM;  // parity 1
    u32* const fl = flags + g * 16;

    // ---- step 0 (one-time VALU): h_1 = cell(x=0, h=hx) ----
    float hold[4];
    {
        float ghr[4] = {0, 0, 0, 0}, ghz[4] = {0, 0, 0, 0}, ghn[4] = {0, 0, 0, 0};
        const float* wr  = w_hh + (size_t)jcol * HDIM;
        const float* wz  = w_hh + (size_t)(256 + jcol) * HDIM;
        const float* wn  = w_hh + (size_t)(512 + jcol) * HDIM;
        const float* hx0 = hx + (size_t)(g * 16 + r0) * HDIM;
        for (int k = 0; k < HDIM; ++k) {
            float fr = wr[k], fz = wz[k], fn = wn[k];
#pragma unroll
            for (int i = 0; i < 4; ++i) {
                float h = hx0[i * HDIM + k];
                ghr[i] += h * fr; ghz[i] += h * fz; ghn[i] += h * fn;
            }
        }
#pragma unroll
        for (int i = 0; i < 4; ++i) {
            float rr = sigm(b_ih[jcol] + b_hh[jcol] + ghr[i]);
            float zz = sigm(b_ih[256 + jcol] + b_hh[256 + jcol] + ghz[i]);
            float nn = tanh_f(b_ih[512 + jcol] + rr * (ghn[i] + b_hh[512 + jcol]));
            float hv = nn + zz * (hx0[i * HDIM + jcol] - nn);
            hold[i] = hv;
            eB[(r0 + i) * HDIM + jcol] = f2bf(hv);   // h_1 -> parity 1
        }
    }
    __builtin_amdgcn_fence(__ATOMIC_RELEASE, "agent");
    if (lane == 0)
        __hip_atomic_store(&fl[w], 1u, __ATOMIC_RELAXED, __HIP_MEMORY_SCOPE_AGENT);

    // ---- main loop: step s reads h_s, writes h_{s+1}, projects t=s-1 ----
    for (int s = 1; s <= 511; ++s) {
        {
            const u32 target = (u32)s;
            bool ok;
            do {
                u32 f = 0xFFFFFFFFu;
                if (lane < 16)
                    f = __hip_atomic_load(&fl[lane], __ATOMIC_RELAXED,
                                          __HIP_MEMORY_SCOPE_AGENT);
                ok = __all((int)(f >= target));
                if (!ok) __builtin_amdgcn_s_sleep(1);
            } while (!ok);
        }
        __builtin_amdgcn_fence(__ATOMIC_ACQUIRE, "agent");

        const u16* hb = (s & 1) ? eB : eA;
        short8 a[8];
#pragma unroll
        for (int kt = 0; kt < 8; ++kt)
            a[kt] = *(const short8*)(hb + col_l * HDIM + kt * 32 + kofs);

        f32x4 acc[4];
#pragma unroll
        for (int n = 0; n < 4; ++n) acc[n] = (f32x4){0.f, 0.f, 0.f, 0.f};
#pragma unroll
        for (int kt = 0; kt < 8; ++kt) {
#pragma unroll
            for (int g4 = 0; g4 < 4; ++g4) {
                acc[g4] = mfma16(a[kt], bhi[g4][kt], acc[g4]);
                acc[g4] = mfma16(a[kt], blo[g4][kt], acc[g4]);
            }
        }

        u16* ho = (s & 1) ? eA : eB;
#pragma unroll
        for (int i = 0; i < 4; ++i) {
            float rr = sigm(acc[0][i] + b_r);
            float zz = sigm(acc[1][i] + b_z);
            float nn = tanh_f(acc[2][i] + b_in + rr * (acc[3][i] + b_hn));
            float hv = nn + zz * (hold[i] - nn);
            hold[i] = hv;
            ho[(r0 + i) * HDIM + jcol] = f2bf(hv);
        }
        __builtin_amdgcn_fence(__ATOMIC_RELEASE, "agent");
        if (lane == 0)
            __hip_atomic_store(&fl[w], (u32)(s + 1), __ATOMIC_RELAXED,
                               __HIP_MEMORY_SCOPE_AGENT);

        // fused out projection for t = s-1 (after flag; ys[t] = h_{t+1} = h_s)
        const int t = s - 1;
        if ((t & 1) == myt) {
            f32x4 oacc = (f32x4){0.f, 0.f, 0.f, 0.f};
#pragma unroll
            for (int kt = 0; kt < 8; ++kt) oacc = mfma16(a[kt], phi[kt], oacc);
#pragma unroll
            for (int i = 0; i < 4; ++i)
                out1[(size_t)(g * 16 + r0 + i) * (NSTEPS * MDIM) +
                     (size_t)t * MDIM + pcol] = oacc[i] + ob;
        }
    }

    // ---- epilogue: t=511 (odd -> myt==1 blocks) from h_512 (parity 0) ----
    if (myt == 1) {
        {
            bool ok;
            do {
                u32 f = 0xFFFFFFFFu;
                if (lane < 16)
                    f = __hip_atomic_load(&fl[lane], __ATOMIC_RELAXED,
                                          __HIP_MEMORY_SCOPE_AGENT);
                ok = __all((int)(f >= 512u));
                if (!ok) __builtin_amdgcn_s_sleep(1);
            } while (!ok);
        }
        __builtin_amdgcn_fence(__ATOMIC_ACQUIRE, "agent");
        short8 a[8];
#pragma unroll
        for (int kt = 0; kt < 8; ++kt)
            a[kt] = *(const short8*)(eA + col_l * HDIM + kt * 32 + kofs);
        f32x4 oacc = (f32x4){0.f, 0.f, 0.f, 0.f};
#pragma unroll
        for (int kt = 0; kt < 8; ++kt) oacc = mfma16(a[kt], phi[kt], oacc);
#pragma unroll
        for (int i = 0; i < 4; ++i)
            out1[(size_t)(g * 16 + r0 + i) * (NSTEPS * MDIM) +
                 511ull * MDIM + pcol] = oacc[i] + ob;
    }

    // ---- hx_final: exact f32 h_512 from hold ----
#pragma unroll
    for (int i = 0; i < 4; ++i)
        out2[(size_t)(g * 16 + r0 + i) * HDIM + jcol] = hold[i];
}

// ---------------------------------------------------------------------------
extern "C" void kernel_launch(void* const* d_in, const int* in_sizes, int n_in,
                              void* d_out, int out_size, void* d_ws, size_t ws_size,
                              hipStream_t stream) {
    const float* P[11];
    for (int i = 0; i < 11 && i < n_in; ++i) P[i] = (const float*)d_in[i];

    // Input-order detection via element-count signature (dict order confirmed
    // by round-6 pass; keep insurance).
    const float *emb, *w1, *b1, *w2, *b2, *w_ih, *b_ih, *w_hh, *b_hh, *ow, *obv;
    if (n_in > 1 && in_sizes[1] == 256) {            // alphabetical
        emb = P[0]; b1 = P[1]; b2 = P[2]; w1 = P[3]; w2 = P[4];
        b_hh = P[5]; b_ih = P[6]; w_hh = P[7]; w_ih = P[8];
        obv = P[9]; ow = P[10];
    } else if (n_in > 1 && in_sizes[1] == 32768) {   // reversed dict
        obv = P[0]; ow = P[1]; b_hh = P[2]; w_hh = P[3]; b_ih = P[4];
        w_ih = P[5]; b2 = P[6]; w2 = P[7]; b1 = P[8]; w1 = P[9]; emb = P[10];
    } else {                                         // dict order (documented)
        emb = P[0]; w1 = P[1]; b1 = P[2]; w2 = P[3]; b2 = P[4];
        w_ih = P[5]; b_ih = P[6]; w_hh = P[7]; b_hh = P[8];
        ow = P[9]; obv = P[10];
    }

    float* out1 = (float*)d_out;                            // [256][512][128] f32
    float* out2 = out1 + (size_t)BATCH * NSTEPS * MDIM;     // [256][256] f32

    // ws layout (~1.97 MB)
    char* ws = (char*)d_ws;
    u16*   Whi   = (u16*)(ws + 0);            // 1152*256*2 = 589824
    u16*   Wlo   = (u16*)(ws + 589824);       // 589824
    float* bias  = (float*)(ws + 1179648);    // 4608
    u32*   flags = (u32*)(ws + 1184256);      // 1024
    u16*   exch  = (u16*)(ws + 1185280);      // 16*2*16*256*2 = 262144
    float* mid   = (float*)(ws + 1447424);    // 262144
    float* hxb   = (float*)(ws + 1709568);    // 262144  (ends 1971712)

    k_prep<<<1152, 256, 0, stream>>>(w_ih, w_hh, b_ih, b_hh, ow, obv,
                                     Whi, Wlo, bias, flags);
    // FNN: hx = relu(emb@w1^T + b1) @ w2^T + b2
    k_gemm_f32<1><<<dim3(16, 16), dim3(16, 16), 0, stream>>>(emb, w1, b1, mid, 256, 256);
    k_gemm_f32<0><<<dim3(16, 16), dim3(16, 16), 0, stream>>>(mid, w2, b2, hxb, 256, 256);
    // Persistent scan (steps 0..511 + fused projection + finals)
    k_scan<<<256, 64, 0, stream>>>(Whi, Wlo, bias, hxb, w_hh, b_ih, b_hh,
                                   exch, flags, out1, out2);
}

// Round 9
// 1754.861 us; speedup vs baseline: 7.5100x; 2.4475x over previous
//
#include <hip/hip_runtime.h>
#include <stdint.h>

// Problem sizes (fixed)
#define BATCH 256
#define HDIM  256
#define MDIM  128
#define NSTEPS 512

typedef unsigned short u16;
typedef unsigned int   u32;
typedef unsigned long long u64;
typedef short short8 __attribute__((ext_vector_type(8)));
typedef float f32x4  __attribute__((ext_vector_type(4)));

__device__ __forceinline__ u16 f2bf(float f) {
    u32 x = __builtin_bit_cast(u32, f);
    u32 r = x + 0x7FFFu + ((x >> 16) & 1u);
    return (u16)(r >> 16);
}
__device__ __forceinline__ float bf2f(u16 h) {
    u32 x = ((u32)h) << 16;
    return __builtin_bit_cast(float, x);
}
__device__ __forceinline__ float sigm(float x) { return 1.f / (1.f + __expf(-x)); }
__device__ __forceinline__ float tanh_f(float x) {
    float ax = fabsf(x);
    float e  = __expf(-2.f * ax);
    float t  = (1.f - e) / (1.f + e);
    return copysignf(t, x);
}
__device__ __forceinline__ f32x4 mfma16(short8 a, short8 b, f32x4 c) {
    return __builtin_amdgcn_mfma_f32_16x16x32_bf16(a, b, c, 0, 0, 0);
}

// ---------------------------------------------------------------------------
// prep: effective weights (x==h for steps>=1 collapses r,z to summed weights),
// bf16 hi/lo split, bias vector, exch zeroing (tag 0 != any step tag).
// Weff rows: [0,256)=r (w_ih+w_hh), [256,512)=z (sum), [512,768)=i_n (w_ih),
//            [768,1024)=h_n (w_hh), [1024,1152)=out_w.  bias same rows.
// ---------------------------------------------------------------------------
__global__ __launch_bounds__(256) void k_prep(
    const float* __restrict__ w_ih, const float* __restrict__ w_hh,
    const float* __restrict__ b_ih, const float* __restrict__ b_hh,
    const float* __restrict__ ow,   const float* __restrict__ obv,
    u16* __restrict__ Whi, u16* __restrict__ Wlo, float* __restrict__ bias,
    u32* __restrict__ exch) {
    int row = blockIdx.x;   // 0..1151
    int c   = threadIdx.x;  // 0..255
    float v;
    if (row < 512)        v = w_ih[row * HDIM + c] + w_hh[row * HDIM + c];
    else if (row < 768)   v = w_ih[row * HDIM + c];
    else if (row < 1024)  v = w_hh[(row - 256) * HDIM + c];
    else                  v = ow[(row - 1024) * HDIM + c];
    u16 hi = f2bf(v);
    u16 lo = f2bf(v - bf2f(hi));
    Whi[(size_t)row * HDIM + c] = hi;
    Wlo[(size_t)row * HDIM + c] = lo;
    if (c == 0) {
        float bv;
        if (row < 512)        bv = b_ih[row] + b_hh[row];
        else if (row < 768)   bv = b_ih[row];
        else if (row < 1024)  bv = b_hh[row - 256];
        else                  bv = obv[row - 1024];
        bias[row] = bv;
    }
    // zero the 131072-u32 exchange buffer (rows 0..511 cover it exactly)
    if (row < 512) exch[row * 256 + c] = 0u;
}

// ---------------------------------------------------------------------------
// f32 tiled GEMM (prologue FNN): out[M][N] = act(A @ W^T + b)
// ---------------------------------------------------------------------------
template <int RELU>
__global__ __launch_bounds__(256) void k_gemm_f32(
    const float* __restrict__ A, const float* __restrict__ W,
    const float* __restrict__ bvec, float* __restrict__ out, int N, int K) {
    __shared__ float At[16][17];
    __shared__ float Wt[16][17];
    int tx = threadIdx.x, ty = threadIdx.y;
    int mrow = blockIdx.x * 16 + ty;
    int nrow = blockIdx.y * 16 + ty;
    float acc = 0.0f;
    for (int k0 = 0; k0 < K; k0 += 16) {
        At[ty][tx] = A[(size_t)mrow * K + k0 + tx];
        Wt[ty][tx] = W[(size_t)nrow * K + k0 + tx];
        __syncthreads();
#pragma unroll
        for (int kk = 0; kk < 16; ++kk) acc += At[ty][kk] * Wt[tx][kk];
        __syncthreads();
    }
    int n = blockIdx.y * 16 + tx;
    float r = acc + bvec[n];
    if (RELU) r = fmaxf(r, 0.0f);
    out[(size_t)mrow * N + n] = r;
}

// ---------------------------------------------------------------------------
// Persistent scan, fence-free: 256 blocks x 64 threads (1 wave).
// Block (g,w): cluster g (16 batch rows), h-cols [16w,16w+16), 4 gate B-frags
// resident (hi+lo). h exchanged as (tag<<16|bf16) u32, double-buffered by
// parity, layout [parity][g][col][row] (consumer loads dense, producer u64
// stores dense). ALL cross-block traffic = relaxed agent atomics; no fences,
// no flags, no L2 writeback/invalidate. Tag-spin provides ordering; depth-2
// buffering + dataflow provides the anti-overwrite credit.
// ---------------------------------------------------------------------------
__global__ __launch_bounds__(64, 1) void k_scan(
    const u16* __restrict__ Whi, const u16* __restrict__ Wlo,
    const float* __restrict__ bias,
    const float* __restrict__ hx, const float* __restrict__ w_hh,
    const float* __restrict__ b_ih, const float* __restrict__ b_hh,
    u32* __restrict__ exch, float* __restrict__ out1, float* __restrict__ out2) {

    const int b    = blockIdx.x;
    const int w    = b >> 4;             // 0..15 col-group
    const int g    = b & 15;             // cluster
    const int lane = threadIdx.x;
    const int col_l = lane & 15;
    const int kgrp  = lane >> 4;
    const int kofs  = kgrp * 8;
    const int r0    = kgrp * 4;          // C rows r0..r0+3 (m89 layout)
    const int jcol  = w * 16 + col_l;    // owned h-column
    const int pcol  = (w & 7) * 16 + col_l;  // owned proj column
    const int myt   = w >> 3;            // project t with (t&1)==myt

    // ---- resident B fragments: gates hi+lo + proj hi ----
    short8 bhi[4][8], blo[4][8], phi[8];
#pragma unroll
    for (int g4 = 0; g4 < 4; ++g4) {
        const u16* base_hi = Whi + (size_t)(g4 * 256 + jcol) * HDIM;
        const u16* base_lo = Wlo + (size_t)(g4 * 256 + jcol) * HDIM;
#pragma unroll
        for (int kt = 0; kt < 8; ++kt) {
            bhi[g4][kt] = *(const short8*)(base_hi + kt * 32 + kofs);
            blo[g4][kt] = *(const short8*)(base_lo + kt * 32 + kofs);
        }
    }
    {
        const u16* base_p = Whi + (size_t)(1024 + pcol) * HDIM;
#pragma unroll
        for (int kt = 0; kt < 8; ++kt)
            phi[kt] = *(const short8*)(base_p + kt * 32 + kofs);
    }

    const float b_r  = bias[jcol];
    const float b_z  = bias[256 + jcol];
    const float b_in = bias[512 + jcol];
    const float b_hn = bias[768 + jcol];
    const float ob   = bias[1024 + pcol];

    // slabs: [parity][g][col][row], 4096 u32 per (parity,g)
    u32* const slab0 = exch + (size_t)(0 * 16 + g) * 4096;
    u32* const slab1 = exch + (size_t)(1 * 16 + g) * 4096;

    // ---- step 0 (one-time VALU): h_1 = cell(x=0, h=hx) -> parity 1, tag 1 ----
    float hold[4];
    {
        float ghr[4] = {0, 0, 0, 0}, ghz[4] = {0, 0, 0, 0}, ghn[4] = {0, 0, 0, 0};
        const float* wr  = w_hh + (size_t)jcol * HDIM;
        const float* wz  = w_hh + (size_t)(256 + jcol) * HDIM;
        const float* wn  = w_hh + (size_t)(512 + jcol) * HDIM;
        const float* hx0 = hx + (size_t)(g * 16 + r0) * HDIM;
        for (int k = 0; k < HDIM; ++k) {
            float fr = wr[k], fz = wz[k], fn = wn[k];
#pragma unroll
            for (int i = 0; i < 4; ++i) {
                float h = hx0[i * HDIM + k];
                ghr[i] += h * fr; ghz[i] += h * fz; ghn[i] += h * fn;
            }
        }
        u32 p[4];
#pragma unroll
        for (int i = 0; i < 4; ++i) {
            float rr = sigm(b_ih[jcol] + b_hh[jcol] + ghr[i]);
            float zz = sigm(b_ih[256 + jcol] + b_hh[256 + jcol] + ghz[i]);
            float nn = tanh_f(b_ih[512 + jcol] + rr * (ghn[i] + b_hh[512 + jcol]));
            float hv = nn + zz * (hx0[i * HDIM + jcol] - nn);
            hold[i] = hv;
            p[i] = (1u << 16) | (u32)f2bf(hv);
        }
        u64* dst = (u64*)(slab1 + jcol * 16 + r0);
        __hip_atomic_store(&dst[0], ((u64)p[1] << 32) | p[0],
                           __ATOMIC_RELAXED, __HIP_MEMORY_SCOPE_AGENT);
        __hip_atomic_store(&dst[1], ((u64)p[3] << 32) | p[2],
                           __ATOMIC_RELAXED, __HIP_MEMORY_SCOPE_AGENT);
    }

    // ---- main loop: step s reads h_s (tag s), writes h_{s+1}, projects t=s-1 ----
    for (int s = 1; s <= 511; ++s) {
        const u32* ein = (s & 1) ? slab1 : slab0;
        u32*      eout = (s & 1) ? slab0 : slab1;
        const u32 tag  = (u32)s;

        short8 a[8];
        for (;;) {
            bool allok = true;
#pragma unroll
            for (int kt = 0; kt < 8; ++kt) {
                u32 v[8];
#pragma unroll
                for (int j = 0; j < 8; ++j)
                    v[j] = __hip_atomic_load(
                        ein + (kt * 32 + kofs + j) * 16 + col_l,
                        __ATOMIC_RELAXED, __HIP_MEMORY_SCOPE_AGENT);
#pragma unroll
                for (int j = 0; j < 8; ++j) {
                    allok = allok && ((v[j] >> 16) == tag);
                    a[kt][j] = (short)(v[j] & 0xFFFFu);
                }
            }
            if (__all((int)allok)) break;
            __builtin_amdgcn_s_sleep(1);
        }

        f32x4 acc[4];
#pragma unroll
        for (int n = 0; n < 4; ++n) acc[n] = (f32x4){0.f, 0.f, 0.f, 0.f};
#pragma unroll
        for (int kt = 0; kt < 8; ++kt) {
#pragma unroll
            for (int g4 = 0; g4 < 4; ++g4) {
                acc[g4] = mfma16(a[kt], bhi[g4][kt], acc[g4]);
                acc[g4] = mfma16(a[kt], blo[g4][kt], acc[g4]);
            }
        }

        u32 pk[4];
#pragma unroll
        for (int i = 0; i < 4; ++i) {
            float rr = sigm(acc[0][i] + b_r);
            float zz = sigm(acc[1][i] + b_z);
            float nn = tanh_f(acc[2][i] + b_in + rr * (acc[3][i] + b_hn));
            float hv = nn + zz * (hold[i] - nn);
            hold[i] = hv;
            pk[i] = ((u32)(s + 1) << 16) | (u32)f2bf(hv);
        }
        {
            u64* dst = (u64*)(eout + jcol * 16 + r0);
            __hip_atomic_store(&dst[0], ((u64)pk[1] << 32) | pk[0],
                               __ATOMIC_RELAXED, __HIP_MEMORY_SCOPE_AGENT);
            __hip_atomic_store(&dst[1], ((u64)pk[3] << 32) | pk[2],
                               __ATOMIC_RELAXED, __HIP_MEMORY_SCOPE_AGENT);
        }

        // fused out projection for t = s-1 (ys[t] = h_{t+1} = h_s = a[])
        const int t = s - 1;
        if ((t & 1) == myt) {
            f32x4 oacc = (f32x4){0.f, 0.f, 0.f, 0.f};
#pragma unroll
            for (int kt = 0; kt < 8; ++kt) oacc = mfma16(a[kt], phi[kt], oacc);
#pragma unroll
            for (int i = 0; i < 4; ++i)
                out1[(size_t)(g * 16 + r0 + i) * (NSTEPS * MDIM) +
                     (size_t)t * MDIM + pcol] = oacc[i] + ob;
        }
    }

    // ---- epilogue: t=511 (myt==1) from h_512 (parity 0, tag 512) ----
    if (myt == 1) {
        short8 a[8];
        for (;;) {
            bool allok = true;
#pragma unroll
            for (int kt = 0; kt < 8; ++kt) {
                u32 v[8];
#pragma unroll
                for (int j = 0; j < 8; ++j)
                    v[j] = __hip_atomic_load(
                        slab0 + (kt * 32 + kofs + j) * 16 + col_l,
                        __ATOMIC_RELAXED, __HIP_MEMORY_SCOPE_AGENT);
#pragma unroll
                for (int j = 0; j < 8; ++j) {
                    allok = allok && ((v[j] >> 16) == 512u);
                    a[kt][j] = (short)(v[j] & 0xFFFFu);
                }
            }
            if (__all((int)allok)) break;
            __builtin_amdgcn_s_sleep(1);
        }
        f32x4 oacc = (f32x4){0.f, 0.f, 0.f, 0.f};
#pragma unroll
        for (int kt = 0; kt < 8; ++kt) oacc = mfma16(a[kt], phi[kt], oacc);
#pragma unroll
        for (int i = 0; i < 4; ++i)
            out1[(size_t)(g * 16 + r0 + i) * (NSTEPS * MDIM) +
                 511ull * MDIM + pcol] = oacc[i] + ob;
    }

    // ---- hx_final: exact f32 h_512 ----
#pragma unroll
    for (int i = 0; i < 4; ++i)
        out2[(size_t)(g * 16 + r0 + i) * HDIM + jcol] = hold[i];
}

// ---------------------------------------------------------------------------
extern "C" void kernel_launch(void* const* d_in, const int* in_sizes, int n_in,
                              void* d_out, int out_size, void* d_ws, size_t ws_size,
                              hipStream_t stream) {
    const float* P[11];
    for (int i = 0; i < 11 && i < n_in; ++i) P[i] = (const float*)d_in[i];

    // Input-order insurance (dict order confirmed by round-6 pass).
    const float *emb, *w1, *b1, *w2, *b2, *w_ih, *b_ih, *w_hh, *b_hh, *ow, *obv;
    if (n_in > 1 && in_sizes[1] == 256) {            // alphabetical
        emb = P[0]; b1 = P[1]; b2 = P[2]; w1 = P[3]; w2 = P[4];
        b_hh = P[5]; b_ih = P[6]; w_hh = P[7]; w_ih = P[8];
        obv = P[9]; ow = P[10];
    } else if (n_in > 1 && in_sizes[1] == 32768) {   // reversed dict
        obv = P[0]; ow = P[1]; b_hh = P[2]; w_hh = P[3]; b_ih = P[4];
        w_ih = P[5]; b2 = P[6]; w2 = P[7]; b1 = P[8]; w1 = P[9]; emb = P[10];
    } else {                                         // dict order (documented)
        emb = P[0]; w1 = P[1]; b1 = P[2]; w2 = P[3]; b2 = P[4];
        w_ih = P[5]; b_ih = P[6]; w_hh = P[7]; b_hh = P[8];
        ow = P[9]; obv = P[10];
    }

    float* out1 = (float*)d_out;                            // [256][512][128] f32
    float* out2 = out1 + (size_t)BATCH * NSTEPS * MDIM;     // [256][256] f32

    // ws layout (~2.13 MB)
    char* ws = (char*)d_ws;
    u16*   Whi  = (u16*)(ws + 0);            // 589824
    u16*   Wlo  = (u16*)(ws + 589824);       // 589824
    float* bias = (float*)(ws + 1179648);    // 4608
    u32*   exch = (u32*)(ws + 1184256);      // 2*16*256*16*4 = 524288
    float* mid  = (float*)(ws + 1708544);    // 262144
    float* hxb  = (float*)(ws + 1970688);    // 262144  (ends 2232832)

    k_prep<<<1152, 256, 0, stream>>>(w_ih, w_hh, b_ih, b_hh, ow, obv,
                                     Whi, Wlo, bias, exch);
    // FNN: hx = relu(emb@w1^T + b1) @ w2^T + b2
    k_gemm_f32<1><<<dim3(16, 16), dim3(16, 16), 0, stream>>>(emb, w1, b1, mid, 256, 256);
    k_gemm_f32<0><<<dim3(16, 16), dim3(16, 16), 0, stream>>>(mid, w2, b2, hxb, 256, 256);
    // Persistent scan (steps 0..511 + fused projection + finals)
    k_scan<<<256, 64, 0, stream>>>(Whi, Wlo, bias, hxb, w_hh, b_ih, b_hh,
                                   exch, out1, out2);
}